// Round 1
// baseline (436.356 us; speedup 1.0000x reference)
//
#include <hip/hip_runtime.h>

// Problem constants (match reference)
#define C_CLASSES 10000
#define K_PROTO   4
#define D_DIM     2048
#define D_VEC     (D_DIM / 4)            // 512 float4 per row
#define CLS_VEC   (K_PROTO * D_VEC)      // 2048 float4 per class (32 KB)
#define NBLOCKS   500                    // 4 waves/block -> 2000 waves, all co-resident
#define NWAVES    (NBLOCKS * 4)          // 2000
#define CPW       (C_CLASSES / NWAVES)   // 5 classes per wave, exact

typedef float v4f __attribute__((ext_vector_type(4)));

// Load one half-class (2 rows, 16 KB) into a register buffer. half in {0,1}.
__device__ __forceinline__ void load_half(v4f (&buf)[2][8], const v4f* __restrict__ p,
                                          const int half, const int lane) {
#pragma unroll
    for (int rr = 0; rr < 2; ++rr)
#pragma unroll
        for (int j = 0; j < 8; ++j)
            buf[rr][j] = p[(half * 2 + rr) * D_VEC + j * 64 + lane];
}

// Per-lane partial squared distances for the 2 rows in buf.
__device__ __forceinline__ void dist_half(const v4f (&buf)[2][8], const v4f (&f)[8],
                                          float& a0, float& a1) {
    float a[2];
#pragma unroll
    for (int rr = 0; rr < 2; ++rr) {
        float s = 0.0f;
#pragma unroll
        for (int j = 0; j < 8; ++j) {
            const float dx = buf[rr][j].x - f[j].x;
            const float dy = buf[rr][j].y - f[j].y;
            const float dz = buf[rr][j].z - f[j].z;
            const float dw = buf[rr][j].w - f[j].w;
            s += dx * dx + dy * dy + dz * dz + dw * dw;
        }
        a[rr] = s;
    }
    a0 = a[0];
    a1 = a[1];
}

// Kernel 1: persistent waves, each owns 5 consecutive classes (160 KB contiguous).
// Double-buffered half-class (2-row, 16 KB) register pipeline: compute A while
// refilling A with the NEXT class's half-0, compute B while refilling half-1.
// Keeps >=16 KB of loads in flight per wave continuously (no one-shot drain,
// no block churn). Online logsumexp across the wave's classes -> one float2.
__global__ __launch_bounds__(256, 2) void dist_kernel(const v4f* __restrict__ proto,
                                                      const v4f* __restrict__ feat,
                                                      const int* __restrict__ label,
                                                      float2* __restrict__ wave_pair,
                                                      float* __restrict__ d_label) {
    const int wave = (blockIdx.x << 2) | (threadIdx.x >> 6);
    const int lane = threadIdx.x & 63;
    const int lbl  = label[0];

    // Feature into registers once (L2-hot, reused by every wave).
    v4f f[8];
#pragma unroll
    for (int j = 0; j < 8; ++j) f[j] = feat[j * 64 + lane];

    const v4f* pc = proto + (size_t)wave * CPW * CLS_VEC;

    v4f A[2][8], B[2][8];
    load_half(A, pc, 0, lane);   // class c0 rows {0,1}
    load_half(B, pc, 1, lane);   // class c0 rows {2,3}

    float m_run = 3.402823466e38f;   // running min d
    float s_run = 0.0f;              // running sum exp(m_run - d)

#pragma unroll
    for (int ci = 0; ci < CPW; ++ci) {
        const bool last = (ci == CPW - 1);
        const v4f* pn = pc + CLS_VEC;    // next class base

        float acc[4];
        dist_half(A, f, acc[0], acc[1]);
        if (!last) load_half(A, pn, 0, lane);   // folded away on last iter
        dist_half(B, f, acc[2], acc[3]);
        if (!last) load_half(B, pn, 1, lane);

        // Transposed reduce. Stage 1: sum each acc within 4-lane groups (bits 0-1).
#pragma unroll
        for (int m = 1; m <= 2; m <<= 1) {
            acc[0] += __shfl_xor(acc[0], m, 64);
            acc[1] += __shfl_xor(acc[1], m, 64);
            acc[2] += __shfl_xor(acc[2], m, 64);
            acc[3] += __shfl_xor(acc[3], m, 64);
        }
        const int l3 = lane & 3;
        float v = acc[0];
        v = (l3 == 1) ? acc[1] : v;
        v = (l3 == 2) ? acc[2] : v;
        v = (l3 == 3) ? acc[3] : v;
        // Stage 2: sum across the 16 groups (bits 2-5). Lane L holds d[4c+(L&3)].
#pragma unroll
        for (int m = 4; m <= 32; m <<= 1) v += __shfl_xor(v, m, 64);

        const int c = wave * CPW + ci;
        if (c == lbl && lane < 4) d_label[lane] = v;   // wave-uniform branch

        // Class-local (min, sumexp) over the 4 rows.
        float mn = fminf(v, __shfl_xor(v, 1, 64));
        mn = fminf(mn, __shfl_xor(mn, 2, 64));
        float s = expf(mn - v);
        s += __shfl_xor(s, 1, 64);
        s += __shfl_xor(s, 2, 64);

        // Online merge into the running pair. First iter: m_run=+inf, s_run=0:
        // s_run*expf(newm-inf) = 0*0 = 0 (no NaN), so this is safe unconditionally.
        const float newm = fminf(m_run, mn);
        s_run = s_run * expf(newm - m_run) + s * expf(newm - mn);
        m_run = newm;

        pc = pn;
    }

    if (lane == 0) wave_pair[wave] = make_float2(m_run, s_run);
}

// Kernel 2: one 1024-thread block combines 2000 wave pairs (16 KB, L2-hot).
__global__ __launch_bounds__(1024) void finalize_kernel(const float4* __restrict__ pairs4,
                                                        const float* __restrict__ d_label,
                                                        float* __restrict__ out) {
    __shared__ float sm[20];
    const int tid  = threadIdx.x;
    const int lane = tid & 63;
    const int wid  = tid >> 6;          // 0..15
    const int N4   = NWAVES / 2;        // 1000 float4 (two pairs each)

    // Pass 1: global min of d.
    float m = 3.402823466e38f;
    for (int i = tid; i < N4; i += 1024) {
        const float4 p = pairs4[i];
        m = fminf(m, fminf(p.x, p.z));
    }
#pragma unroll
    for (int off = 1; off < 64; off <<= 1) m = fminf(m, __shfl_xor(m, off, 64));
    if (lane == 0) sm[wid] = m;
    __syncthreads();
    if (tid == 0) {
        float mm = sm[0];
#pragma unroll
        for (int i = 1; i < 16; ++i) mm = fminf(mm, sm[i]);
        sm[16] = mm;
    }
    __syncthreads();
    const float dmin = sm[16];

    // Pass 2: sum of S_w * exp(dmin - min_w).
    float acc = 0.0f;
    for (int i = tid; i < N4; i += 1024) {
        const float4 p = pairs4[i];
        acc += p.y * expf(dmin - p.x) + p.w * expf(dmin - p.z);
    }
#pragma unroll
    for (int off = 1; off < 64; off <<= 1) acc += __shfl_xor(acc, off, 64);
    if (lane == 0) sm[wid] = acc;
    __syncthreads();
    if (tid == 0) {
        float ss = 0.0f;
#pragma unroll
        for (int i = 0; i < 16; ++i) ss += sm[i];
        const float log_one = -dmin + logf(ss);
        float p = 0.0f;
#pragma unroll
        for (int k = 0; k < K_PROTO; ++k) p += log_one + d_label[k];
        out[0] = p;
    }
}

extern "C" void kernel_launch(void* const* d_in, const int* in_sizes, int n_in,
                              void* d_out, int out_size, void* d_ws, size_t ws_size,
                              hipStream_t stream) {
    const float* feat  = (const float*)d_in[0];   // [2048] f32
    const int*   label = (const int*)d_in[1];     // [1] int32
    const float* proto = (const float*)d_in[2];   // [10000,4,2048] f32
    float* out = (float*)d_out;                   // [1] f32

    float2* wave_pair = (float2*)d_ws;            // [2000] (min, sumexp)
    float*  d_label   = (float*)(wave_pair + NWAVES);  // [4]

    dist_kernel<<<NBLOCKS, 256, 0, stream>>>(
        (const v4f*)proto, (const v4f*)feat, label, wave_pair, d_label);
    finalize_kernel<<<1, 1024, 0, stream>>>((const float4*)wave_pair, d_label, out);
}

// Round 2
// 408.331 us; speedup vs baseline: 1.0686x; 1.0686x over previous
//
#include <hip/hip_runtime.h>

// Problem constants (match reference)
#define C_CLASSES 10000
#define K_PROTO   4
#define D_DIM     2048
#define ROWS      (C_CLASSES * K_PROTO)   // 40000
#define D_VEC     (D_DIM / 4)             // 512 float4 per row
#define NBLOCKS   (ROWS / 4)              // 4 waves/block, 1 row/wave -> 10000 blocks

typedef float v4f __attribute__((ext_vector_type(4)));

// Kernel 1: one wave per row. Minimal register footprint (~80 VGPR -> 6
// waves/SIMD, 24 waves/CU) so the CU's memory pipe stays saturated by TLP,
// not by per-wave buffer depth. Wave loads its 8 KB row (nontemporal,
// streamed once, issued before the L1-hot feature loads), accumulates the
// squared distance in FMA form, 6-step butterfly, lane 0 writes d[row].
__global__ __launch_bounds__(256) void dist_kernel(const v4f* __restrict__ proto,
                                                   const v4f* __restrict__ feat,
                                                   float* __restrict__ dout) {
    const int row  = (blockIdx.x << 2) | (threadIdx.x >> 6);   // 0..39999
    const int lane = threadIdx.x & 63;
    const v4f* p   = proto + (size_t)row * D_VEC;

    // HBM row loads first (in flight while feature loads resolve from L1/L2).
    v4f r[8];
#pragma unroll
    for (int j = 0; j < 8; ++j)
        r[j] = __builtin_nontemporal_load(&p[j * 64 + lane]);

    v4f f[8];
#pragma unroll
    for (int j = 0; j < 8; ++j) f[j] = feat[j * 64 + lane];

    float a = 0.0f;
#pragma unroll
    for (int j = 0; j < 8; ++j) {
        const float dx = r[j].x - f[j].x;
        const float dy = r[j].y - f[j].y;
        const float dz = r[j].z - f[j].z;
        const float dw = r[j].w - f[j].w;
        a = fmaf(dx, dx, a);
        a = fmaf(dy, dy, a);
        a = fmaf(dz, dz, a);
        a = fmaf(dw, dw, a);
    }

#pragma unroll
    for (int m = 1; m <= 32; m <<= 1) a += __shfl_xor(a, m, 64);

    if (lane == 0) dout[row] = a;
}

// Kernel 2: one 1024-thread block does the full logsumexp over 40000 d's
// (160 KB, L2-hot) and the label-row sum. Two passes: global min, then
// sum of exp(dmin - d). probability = sum_k (log_one + d[label*4+k]).
__global__ __launch_bounds__(1024) void finalize_kernel(const float4* __restrict__ d4,
                                                        const int* __restrict__ label,
                                                        float* __restrict__ out) {
    __shared__ float sm[20];
    const int tid  = threadIdx.x;
    const int lane = tid & 63;
    const int wid  = tid >> 6;          // 0..15
    const int N4   = ROWS / 4;          // 10000 float4

    // Pass 1: global min of d.
    float m = 3.402823466e38f;
    for (int i = tid; i < N4; i += 1024) {
        const float4 p = d4[i];
        m = fminf(m, fminf(fminf(p.x, p.y), fminf(p.z, p.w)));
    }
#pragma unroll
    for (int off = 1; off < 64; off <<= 1) m = fminf(m, __shfl_xor(m, off, 64));
    if (lane == 0) sm[wid] = m;
    __syncthreads();
    if (tid == 0) {
        float mm = sm[0];
#pragma unroll
        for (int i = 1; i < 16; ++i) mm = fminf(mm, sm[i]);
        sm[16] = mm;
    }
    __syncthreads();
    const float dmin = sm[16];

    // Pass 2: sum of exp(dmin - d).
    float acc = 0.0f;
    for (int i = tid; i < N4; i += 1024) {
        const float4 p = d4[i];
        acc += expf(dmin - p.x) + expf(dmin - p.y) + expf(dmin - p.z) + expf(dmin - p.w);
    }
#pragma unroll
    for (int off = 1; off < 64; off <<= 1) acc += __shfl_xor(acc, off, 64);
    if (lane == 0) sm[wid] = acc;
    __syncthreads();
    if (tid == 0) {
        float ss = 0.0f;
#pragma unroll
        for (int i = 0; i < 16; ++i) ss += sm[i];
        const float log_one = -dmin + logf(ss);
        const float* d = (const float*)d4;
        const int lbl = label[0];
        float p = 0.0f;
#pragma unroll
        for (int k = 0; k < K_PROTO; ++k) p += log_one + d[lbl * K_PROTO + k];
        out[0] = p;
    }
}

extern "C" void kernel_launch(void* const* d_in, const int* in_sizes, int n_in,
                              void* d_out, int out_size, void* d_ws, size_t ws_size,
                              hipStream_t stream) {
    const float* feat  = (const float*)d_in[0];   // [2048] f32
    const int*   label = (const int*)d_in[1];     // [1] int32
    const float* proto = (const float*)d_in[2];   // [10000,4,2048] f32
    float* out = (float*)d_out;                   // [1] f32

    float* d = (float*)d_ws;                      // [40000] squared distances

    dist_kernel<<<NBLOCKS, 256, 0, stream>>>((const v4f*)proto, (const v4f*)feat, d);
    finalize_kernel<<<1, 1024, 0, stream>>>((const float4*)d, label, out);
}